// Round 13
// baseline (279.139 us; speedup 1.0000x reference)
//
#include <hip/hip_runtime.h>
#include <cmath>

// Problem dims
#define TN 4
#define TC1 256
#define TCH 128
#define TC2 256
#define TH 80
#define TW 80
#define THP 82
#define TWP 84
#define NPIX (TN*TH*TW)   // 25600

// Workspace layout (float offsets). Total = 17,356,288 floats = 69.4 MB.
#define OFF_WBF   0         // bf16 wbf[co][tap*256+ci], s1-folded: 294912 shorts
#define OFF_W2B   294912    // bf16 [co][ci=128], s2-folded: 32768 shorts
#define OFF_INWB  327680    // bf16 [co][ci=256]: 65536 shorts
#define OFF_OUTWB 393216    // bf16 [co][ci=256], s3-folded: 65536 shorts
#define OFF_DWT   458752    // fp32 [tap][c] 2304
#define OFF_WCAT  461056    // bf16 [j<32][c=256] 8192 shorts
#define OFF_WCATB 467968    // fp32 27
#define OFF_T1    468128    // 128
#define OFF_T2    468512    // 256
#define OFF_T3P   469024    // 256
#define OFF_XPAD  469504    // bf16 NHWC padded x: ends 3,997,696
// aliases (liveness chain, stream order):
#define OFF_Y2N   7525888   // bf16 y2 [25600][256]
#define OFF_RAWN  10802688  // fp32 raw [25600][27]
#define OFF_XPJ   11493888  // bf16 xproj [25600][256] (moved off d_out: dcnpo reads it while writing out)

typedef __attribute__((ext_vector_type(8))) short bf16x8;
typedef __attribute__((ext_vector_type(4))) float f32x4;

__device__ __forceinline__ float siluf(float v) { return v / (1.f + expf(-v)); }
__device__ __forceinline__ short rnbf(float f) {
  unsigned u = __float_as_uint(f);
  unsigned r = (u + 0x7fffu + ((u >> 16) & 1u)) >> 16;
  return (short)r;
}
__device__ __forceinline__ float bf2f(short s) {
  return __uint_as_float(((unsigned)(unsigned short)s) << 16);
}

// ---------------- prep (weights) + padx (x -> bf16 NHWC padded), MERGED ----------------
__global__ __launch_bounds__(256) void k_prep(
    const float* __restrict__ w1, const float* __restrict__ g1, const float* __restrict__ b1,
    const float* __restrict__ m1, const float* __restrict__ v1,
    const float* __restrict__ w2, const float* __restrict__ g2, const float* __restrict__ b2,
    const float* __restrict__ m2, const float* __restrict__ v2,
    const float* __restrict__ dww, const float* __restrict__ offw, const float* __restrict__ offb,
    const float* __restrict__ mskw, const float* __restrict__ mskb,
    const float* __restrict__ inw, const float* __restrict__ outw, const float* __restrict__ outb,
    const float* __restrict__ g3, const float* __restrict__ b3,
    const float* __restrict__ m3, const float* __restrict__ v3,
    const float* __restrict__ x, float* __restrict__ ws)
{
  __shared__ short lds[80 * 40];
  if (blockIdx.x >= 1836) {
    // ---- padx body ----
    short* xpn = (short*)(ws + OFF_XPAD);
    int b = blockIdx.x - 1836;
    int cc = b & 7; int hp = (b >> 3) % THP; int n = b / (THP * 8);
    int c0 = cc * 32;
    int t = threadIdx.x;
    int h = hp - 1;
    bool hv = (h >= 0 && h < TH);
    if (hv) {
      for (int f = t; f < 640; f += 256) {          // 32 ci x 20 float4
        int ci = f / 20; int w4 = (f - ci * 20) * 4;
        float4 xv = *(const float4*)(x + ((n * TC1 + c0 + ci) * TH + h) * TW + w4);
        lds[(w4 + 0) * 40 + ci] = rnbf(xv.x);
        lds[(w4 + 1) * 40 + ci] = rnbf(xv.y);
        lds[(w4 + 2) * 40 + ci] = rnbf(xv.z);
        lds[(w4 + 3) * 40 + ci] = rnbf(xv.w);
      }
    }
    __syncthreads();
    short* op = xpn + ((n * THP + hp) * TWP) * TC2 + c0;
    for (int g = t; g < 672; g += 256) {            // 84 wp x 8 ci4
      int ci4 = (g & 7) * 4; int wp = g >> 3;
      short4 v = {0, 0, 0, 0};
      if (hv && wp >= 1 && wp <= TW) v = *(const short4*)(&lds[(wp - 1) * 40 + ci4]);
      *(short4*)(op + wp * TC2 + ci4) = v;
    }
    return;
  }
  // ---- prep body ----
  int i = blockIdx.x * 256 + threadIdx.x;
  if (i < 294912) {
    int co = i / 2304; int r = i - co * 2304;
    int tap = r >> 8; int ci = r & 255; int ky = tap / 3; int kx = tap - ky * 3;
    float s = g1[co] * __frsqrt_rn(v1[co] + 1e-5f);
    ((short*)(ws + OFF_WBF))[i] = rnbf(w1[((co * TC1 + ci) * 3 + ky) * 3 + kx] * s);
    return;
  }
  i -= 294912;
  if (i < 32768) {
    int co = i >> 7; int ci = i & 127;
    float s = g2[co] * __frsqrt_rn(v2[co] + 1e-5f);
    ((short*)(ws + OFF_W2B))[i] = rnbf(w2[co * TCH + ci] * s);
    return;
  }
  i -= 32768;
  if (i < 65536) {
    int co = i >> 8; int ci = i & 255;
    ((short*)(ws + OFF_INWB))[i] = rnbf(inw[co * TC2 + ci]);
    return;
  }
  i -= 65536;
  if (i < 65536) {
    int co = i >> 8; int ci = i & 255;
    float s = g3[co] * __frsqrt_rn(v3[co] + 1e-5f);
    ((short*)(ws + OFF_OUTWB))[i] = rnbf(outw[co * TC2 + ci] * s);
    return;
  }
  i -= 65536;
  if (i < 2304) { int c = i & 255; int j = i >> 8; ws[OFF_DWT + i] = dww[c * 9 + j]; return; }
  i -= 2304;
  if (i < 8192) {
    int c = i & 255; int j = i >> 8;
    float v = 0.f;
    if (j < 18) v = offw[j * 256 + c];
    else if (j < 27) v = mskw[(j - 18) * 256 + c];
    ((short*)(ws + OFF_WCAT))[i] = rnbf(v);
    return;
  }
  i -= 8192;
  if (i < 27) { ws[OFF_WCATB + i] = (i < 18) ? offb[i] : mskb[i - 18]; return; }
  i -= 27;
  if (i < 128) { float s = g1[i] / sqrtf(v1[i] + 1e-5f); ws[OFF_T1 + i] = b1[i] - m1[i] * s; return; }
  i -= 128;
  if (i < 256) { float s = g2[i] / sqrtf(v2[i] + 1e-5f); ws[OFF_T2 + i] = b2[i] - m2[i] * s; return; }
  i -= 256;
  if (i < 256) { float s = g3[i] / sqrtf(v3[i] + 1e-5f); ws[OFF_T3P + i] = outb[i] * s + b3[i] - m3[i] * s; return; }
}

// ---------------- cv1 + cv2 FUSED (unchanged from R11; 52.4us measured) ----------------
#define BH_STR 40    // halo pixel stride (shorts)
#define BH_PIX 108   // 6 x 18 halo pixels
#define BH_ELE (BH_PIX * BH_STR)   // 4320 shorts per buffer
#define Y1_STR 136   // y1 tile row stride (shorts): 128 + 8 pad
__global__ __launch_bounds__(256) void k_cv12(const short* __restrict__ xpn, const short* __restrict__ wbf,
                                              const short* __restrict__ w2b,
                                              const float* __restrict__ t1v, const float* __restrict__ t2v,
                                              short* __restrict__ y2b)
{
  __shared__ short U[64 * Y1_STR];   // 17,408 B; aliases Bh[2][BH_ELE] (17,280 B)

  int b = blockIdx.x;
  int wt = b % 5; b /= 5; int ht = b % 20; int n = b / 20;
  int w0 = wt * 16, h0 = ht * 4;

  int tid = threadIdx.x;
  int wave = tid >> 6, lane = tid & 63;
  int ln = lane & 15, q = lane >> 4;
  int co0 = wave * 32;

  // ---- phase 1: cv1 ----
  int u0 = tid, u1 = tid + 256;
  int p0 = u0 >> 2, s0 = u0 & 3;
  int p1 = u1 >> 2, s1 = u1 & 3;
  int hh0 = p0 / 18, ww0 = p0 - hh0 * 18;
  int hh1 = p1 / 18, ww1 = p1 - hh1 * 18;
  const short* sb0 = xpn + ((n * THP + h0 + hh0) * TWP + (w0 + ww0)) * 256 + s0 * 8;
  const short* sb1 = xpn + ((n * THP + h0 + hh1) * TWP + (w0 + ww1)) * 256 + s1 * 8;
  bool hasu1 = (u1 < 432);
  int d0 = p0 * BH_STR + s0 * 8;
  int d1 = p1 * BH_STR + s1 * 8;

  const short* abase = wbf + (co0 + ln) * 2304 + q * 8;

  f32x4 acc[2][4];
#pragma unroll
  for (int i = 0; i < 2; ++i)
#pragma unroll
    for (int j = 0; j < 4; ++j) acc[i][j] = (f32x4){0.f, 0.f, 0.f, 0.f};

  bf16x8 rb0 = *(const bf16x8*)(sb0);
  bf16x8 rb1 = {0, 0, 0, 0, 0, 0, 0, 0};
  if (hasu1) rb1 = *(const bf16x8*)(sb1);
  *(bf16x8*)(&U[d0]) = rb0;
  if (hasu1) *(bf16x8*)(&U[d1]) = rb1;
  __syncthreads();

  for (int cc = 0; cc < 8; ++cc) {
    int cur = cc & 1;
    bf16x8 af[9][2];
#pragma unroll
    for (int tap = 0; tap < 9; ++tap)
#pragma unroll
      for (int mt = 0; mt < 2; ++mt)
        af[tap][mt] = *(const bf16x8*)(abase + (mt * 16) * 2304 + tap * 256 + cc * 32);
    if (cc < 7) {
      rb0 = *(const bf16x8*)(sb0 + (cc + 1) * 32);
      if (hasu1) rb1 = *(const bf16x8*)(sb1 + (cc + 1) * 32);
    }
#pragma unroll
    for (int tap = 0; tap < 9; ++tap) {
      const int ky = tap / 3, kx = tap - (tap / 3) * 3;
      bf16x8 bv[4];
#pragma unroll
      for (int nt = 0; nt < 4; ++nt) {
        int pr = nt * 16 + ln;
        int hr = pr >> 4, wc = pr & 15;
        bv[nt] = *(const bf16x8*)(&U[cur * BH_ELE + ((hr + ky) * 18 + (wc + kx)) * BH_STR + q * 8]);
      }
#pragma unroll
      for (int mt = 0; mt < 2; ++mt)
#pragma unroll
        for (int nt = 0; nt < 4; ++nt)
          acc[mt][nt] = __builtin_amdgcn_mfma_f32_16x16x32_bf16(af[tap][mt], bv[nt], acc[mt][nt], 0, 0, 0);
    }
    if (cc < 7) {
      *(bf16x8*)(&U[(cur ^ 1) * BH_ELE + d0]) = rb0;
      if (hasu1) *(bf16x8*)(&U[(cur ^ 1) * BH_ELE + d1]) = rb1;
      __syncthreads();
    }
  }

  // ---- phase 2: y1 tile -> LDS, K=128 GEMM -> y2 ----
  __syncthreads();
#pragma unroll
  for (int mt = 0; mt < 2; ++mt) {
    int co = co0 + mt * 16 + q * 4;
    float t0 = t1v[co], t1 = t1v[co + 1], t2 = t1v[co + 2], t3 = t1v[co + 3];
#pragma unroll
    for (int nt = 0; nt < 4; ++nt) {
      int px = nt * 16 + ln;
      short4 p;
      p.x = rnbf(siluf(acc[mt][nt][0] + t0));
      p.y = rnbf(siluf(acc[mt][nt][1] + t1));
      p.z = rnbf(siluf(acc[mt][nt][2] + t2));
      p.w = rnbf(siluf(acc[mt][nt][3] + t3));
      *(short4*)(&U[px * Y1_STR + co]) = p;
    }
  }
  __syncthreads();

  int coh2 = wave * 64;
  const short* a2base = w2b + (coh2 + ln) * TCH + q * 8;

  f32x4 acc2[4][4];
#pragma unroll
  for (int i = 0; i < 4; ++i)
#pragma unroll
    for (int j = 0; j < 4; ++j) acc2[i][j] = (f32x4){0.f, 0.f, 0.f, 0.f};

#pragma unroll
  for (int c = 0; c < 4; ++c) {
    bf16x8 a2[4], b2[4];
#pragma unroll
    for (int mt = 0; mt < 4; ++mt)
      a2[mt] = *(const bf16x8*)(a2base + (mt * 16) * TCH + c * 32);
#pragma unroll
    for (int nt = 0; nt < 4; ++nt)
      b2[nt] = *(const bf16x8*)(&U[(nt * 16 + ln) * Y1_STR + c * 32 + q * 8]);
#pragma unroll
    for (int mt = 0; mt < 4; ++mt)
#pragma unroll
      for (int nt = 0; nt < 4; ++nt)
        acc2[mt][nt] = __builtin_amdgcn_mfma_f32_16x16x32_bf16(a2[mt], b2[nt], acc2[mt][nt], 0, 0, 0);
  }

#pragma unroll
  for (int mt = 0; mt < 4; ++mt) {
    int co = coh2 + mt * 16 + q * 4;
    float t0 = t2v[co], t1 = t2v[co + 1], t2 = t2v[co + 2], t3 = t2v[co + 3];
#pragma unroll
    for (int nt = 0; nt < 4; ++nt) {
      int pr = nt * 16 + ln;
      int hr = pr >> 4, wc = pr & 15;
      int pix = (n * TH + h0 + hr) * TW + (w0 + wc);
      short4 p;
      p.x = rnbf(siluf(acc2[mt][nt][0] + t0));
      p.y = rnbf(siluf(acc2[mt][nt][1] + t1));
      p.z = rnbf(siluf(acc2[mt][nt][2] + t2));
      p.w = rnbf(siluf(acc2[mt][nt][3] + t3));
      *(short4*)(y2b + pix * TC2 + co) = p;
    }
  }
}

// ---------------- proj_in + dwln/offmask MERGED (unchanged from R11) ----------------
#define A_STR 40
#define DT_STR 264
__global__ __launch_bounds__(256) void k_pidw(
    const short* __restrict__ y2b, const short* __restrict__ inwb, const float* __restrict__ inb,
    short* __restrict__ xproj,
    const float* __restrict__ dwt, const float* __restrict__ dwb, const float* __restrict__ lng,
    const float* __restrict__ lnb, const short* __restrict__ wcatb16, const float* __restrict__ wcatb,
    float* __restrict__ raw)
{
  __shared__ short smem[4 * 128 * A_STR];   // 81920 B union

  int tid = threadIdx.x;
  int wave = tid >> 6, lane = tid & 63;

  if (blockIdx.x < 400) {
    // ======== proj_in body ========
    short (*As)[128 * A_STR] = (short(*)[128 * A_STR])(smem);
    short (*Bs)[128 * A_STR] = (short(*)[128 * A_STR])(smem + 2 * 128 * A_STR);

    int b = blockIdx.x;
    int ch = b & 1; int pt = b >> 1;
    int co_base = ch * 128;
    int pix0 = pt * 128;

    int ln = lane & 15, q = lane >> 4;
    int coh = (wave & 1) * 64;
    int pxh = (wave >> 1) * 64;

    int srow = tid >> 1;
    int ssub = (tid & 1) * 16;
    const short* arow = inwb + (co_base + srow) * TC2 + ssub;
    const short* brow = y2b + (pix0 + srow) * TC2 + ssub;

    f32x4 acc[4][4];
#pragma unroll
    for (int i = 0; i < 4; ++i)
#pragma unroll
      for (int j = 0; j < 4; ++j) acc[i][j] = (f32x4){0.f, 0.f, 0.f, 0.f};

    bf16x8 ra0, ra1, rb0, rb1;
    auto grab = [&](int c) {
      const short* ap = arow + c * 32;
      const short* bp = brow + c * 32;
      ra0 = *(const bf16x8*)(ap);
      ra1 = *(const bf16x8*)(ap + 8);
      rb0 = *(const bf16x8*)(bp);
      rb1 = *(const bf16x8*)(bp + 8);
    };
    auto put = [&](int buf) {
      int o = srow * A_STR + ssub;
      *(bf16x8*)(&As[buf][o])     = ra0;
      *(bf16x8*)(&As[buf][o + 8]) = ra1;
      *(bf16x8*)(&Bs[buf][o])     = rb0;
      *(bf16x8*)(&Bs[buf][o + 8]) = rb1;
    };
    auto comp = [&](int buf) {
      bf16x8 af[4], bfv[4];
#pragma unroll
      for (int mt = 0; mt < 4; ++mt)
        af[mt] = *(const bf16x8*)(&As[buf][(coh + mt * 16 + ln) * A_STR + q * 8]);
#pragma unroll
      for (int nt = 0; nt < 4; ++nt)
        bfv[nt] = *(const bf16x8*)(&Bs[buf][(pxh + nt * 16 + ln) * A_STR + q * 8]);
#pragma unroll
      for (int mt = 0; mt < 4; ++mt)
#pragma unroll
        for (int nt = 0; nt < 4; ++nt)
          acc[mt][nt] = __builtin_amdgcn_mfma_f32_16x16x32_bf16(af[mt], bfv[nt], acc[mt][nt], 0, 0, 0);
    };

    const int NCH = TC2 / 32;
    grab(0);
    put(0);
    __syncthreads();
    for (int c = 0; c < NCH; ++c) {
      if (c < NCH - 1) grab(c + 1);
      comp(c & 1);
      if (c < NCH - 1) {
        __syncthreads();
        put((c + 1) & 1);
        __syncthreads();
      }
    }

#pragma unroll
    for (int mt = 0; mt < 4; ++mt) {
      int co = co_base + coh + mt * 16 + q * 4;
      float b0 = inb[co], b1 = inb[co + 1], b2 = inb[co + 2], b3 = inb[co + 3];
#pragma unroll
      for (int nt = 0; nt < 4; ++nt) {
        int pix = pix0 + pxh + nt * 16 + ln;
        short4 p;
        p.x = rnbf(acc[mt][nt][0] + b0);
        p.y = rnbf(acc[mt][nt][1] + b1);
        p.z = rnbf(acc[mt][nt][2] + b2);
        p.w = rnbf(acc[mt][nt][3] + b3);
        *(short4*)(xproj + pix * TC2 + co) = p;
      }
    }
    return;
  }

  // ======== dwom body ========
  short* dt = smem;   // 32 x DT_STR = 8448 shorts

  int half = lane >> 5;
  int c0 = (lane & 31) * 8;
  int pix0 = (blockIdx.x - 400) * 32;

  float4 db0 = *(const float4*)(dwb + c0);
  float4 db1 = *(const float4*)(dwb + c0 + 4);
  float4 g0 = *(const float4*)(lng + c0);
  float4 g1 = *(const float4*)(lng + c0 + 4);
  float4 lb0 = *(const float4*)(lnb + c0);
  float4 lb1 = *(const float4*)(lnb + c0 + 4);
  float gv[8] = {g0.x, g0.y, g0.z, g0.w, g1.x, g1.y, g1.z, g1.w};
  float bvv[8] = {lb0.x, lb0.y, lb0.z, lb0.w, lb1.x, lb1.y, lb1.z, lb1.w};
  const float is2 = 0.70710678118654752f;

  for (int r = 0; r < 4; ++r) {
    int pl = wave * 8 + half * 4 + r;
    int pix = pix0 + pl;
    int w = pix % TW; int h = (pix / TW) % TH; int n = pix / (TH * TW);
    float v[8] = {db0.x, db0.y, db0.z, db0.w, db1.x, db1.y, db1.z, db1.w};
#pragma unroll
    for (int dy = 0; dy < 3; ++dy) {
#pragma unroll
      for (int dx = 0; dx < 3; ++dx) {
        int hh = h + dy - 1, ww = w + dx - 1;
        bool ok = (hh >= 0) & (hh < TH) & (ww >= 0) & (ww < TW);
        int off = ok ? (((n * TH + hh) * TW + ww) * TC2 + c0) : c0;
        bf16x8 yv = *(const bf16x8*)(y2b + off);
        float m = ok ? 1.f : 0.f;
        const float* wp = dwt + (dy * 3 + dx) * TC2 + c0;
        float4 w0 = *(const float4*)(wp);
        float4 w1 = *(const float4*)(wp + 4);
        v[0] += bf2f(yv[0]) * w0.x * m;
        v[1] += bf2f(yv[1]) * w0.y * m;
        v[2] += bf2f(yv[2]) * w0.z * m;
        v[3] += bf2f(yv[3]) * w0.w * m;
        v[4] += bf2f(yv[4]) * w1.x * m;
        v[5] += bf2f(yv[5]) * w1.y * m;
        v[6] += bf2f(yv[6]) * w1.z * m;
        v[7] += bf2f(yv[7]) * w1.w * m;
      }
    }
    float sv = 0.f, sq = 0.f;
#pragma unroll
    for (int i = 0; i < 8; ++i) { sv += v[i]; sq += v[i] * v[i]; }
#pragma unroll
    for (int o = 16; o > 0; o >>= 1) { sv += __shfl_xor(sv, o); sq += __shfl_xor(sq, o); }
    float mu = sv * (1.f / 256.f);
    float var = sq * (1.f / 256.f) - mu * mu;
    float rs = 1.f / sqrtf(var + 1e-6f);
    bf16x8 o8;
#pragma unroll
    for (int i = 0; i < 8; ++i) {
      float nv = (v[i] - mu) * rs * gv[i] + bvv[i];
      o8[i] = rnbf(0.5f * nv * (1.f + erff(nv * is2)));
    }
    *(bf16x8*)(&dt[pl * DT_STR + c0]) = o8;
  }
  __syncthreads();

  int ln = lane & 15, q = lane >> 4;
  int g = wave & 1;
  int jbase = (wave >> 1) * 16;

  f32x4 acc = {0.f, 0.f, 0.f, 0.f};
  const short* ap = wcatb16 + (jbase + ln) * 256 + q * 8;
  const short* bp = &dt[(g * 16 + ln) * DT_STR + q * 8];
#pragma unroll
  for (int kk = 0; kk < 256; kk += 32) {
    bf16x8 a  = *(const bf16x8*)(ap + kk);
    bf16x8 bf = *(const bf16x8*)(bp + kk);
    acc = __builtin_amdgcn_mfma_f32_16x16x32_bf16(a, bf, acc, 0, 0, 0);
  }

  int pix = pix0 + g * 16 + ln;
#pragma unroll
  for (int r = 0; r < 4; ++r) {
    int j = jbase + q * 4 + r;
    if (j < 27) raw[pix * 27 + j] = acc[r] + wcatb[j];
  }
}

// ---------------- DCN gather + output_proj FUSED: z stays in LDS ----------------
// Grid 1600, 16 px/block. Phase 1: sp setup (16x36 taps) + gather (4 px/wave, 8 ch/lane)
// -> z tile [16][264] bf16 in LDS. Phase 2: GEMM 256co x 16px (K=256, 8 steps; A per-lane
// from L2-hot 128KB outwb, B from LDS) + BN + SiLU + residual -> out (64B segments).
// Deletes k_proj_out dispatch and the 13MB z write + 13MB z read.
__global__ __launch_bounds__(256) void k_dcnpo(const short* __restrict__ xproj, const float* __restrict__ raw,
                                               const short* __restrict__ outwb, const float* __restrict__ t3p,
                                               const float* __restrict__ x, float* __restrict__ out)
{
  __shared__ int2 sp[16][36];        // 4608 B
  __shared__ short zt[16 * DT_STR]; // 8448 B

  int tid = threadIdx.x;
  int pixbase = blockIdx.x * 16;
  int n = pixbase / (TH * TW);       // 6400 % 16 == 0: block stays in one image

  for (int j = tid; j < 576; j += 256) {
    int pxl = j / 36, t = j - pxl * 36;
    int pix = pixbase + pxl;
    int w = pix % TW; int h = (pix / TW) % TH;
    const float* r = raw + pix * 27;
    int k = t >> 2, tap = t & 3;
    int tx = tap & 1, ty = tap >> 1;
    float mx = r[18];
#pragma unroll
    for (int kk = 1; kk < 9; ++kk) mx = fmaxf(mx, r[18 + kk]);
    float sum = 0.f, ek = 0.f;
#pragma unroll
    for (int kk = 0; kk < 9; ++kk) {
      float ee = expf(r[18 + kk] - mx);
      sum += ee;
      if (kk == k) ek = ee;
    }
    float mk = ek / sum;
    float px = (float)(w + k / 3) + r[2 * k];
    float py = (float)(h + k % 3) + r[2 * k + 1];
    float x0f = floorf(px), y0f = floorf(py);
    float lw = px - x0f, lh = py - y0f;
    int x0 = (int)x0f + tx, y0 = (int)y0f + ty;
    float wt = mk * (tx ? lw : 1.f - lw) * (ty ? lh : 1.f - lh);
    bool valid = (x0 >= 1) & (x0 <= TW) & (y0 >= 1) & (y0 <= TH);
    int2 pr;
    pr.x = valid ? (((y0 - 1) * TW + (x0 - 1)) * TC2) : 0;
    pr.y = valid ? __float_as_int(wt) : 0;
    sp[pxl][t] = pr;
  }
  __syncthreads();

  int wave = tid >> 6, lane = tid & 63;
  int half = lane >> 5;
  int c0 = (lane & 31) * 8;
  const short* xb = xproj + n * (TH * TW * TC2) + c0;

  for (int r = 0; r < 2; ++r) {
    int pxl = wave * 4 + half * 2 + r;
    float a[8] = {0.f, 0.f, 0.f, 0.f, 0.f, 0.f, 0.f, 0.f};
#pragma unroll
    for (int t = 0; t < 36; ++t) {
      int2 pr = sp[pxl][t];
      float wt = __int_as_float(pr.y);
      bf16x8 v = *(const bf16x8*)(xb + pr.x);
#pragma unroll
      for (int i = 0; i < 8; ++i) a[i] += wt * bf2f(v[i]);
    }
    bf16x8 o8;
#pragma unroll
    for (int i = 0; i < 8; ++i) o8[i] = rnbf(a[i]);
    *(bf16x8*)(&zt[pxl * DT_STR + c0]) = o8;
  }
  __syncthreads();

  // ---- GEMM: out[16px][256co] = outwb(256x256) @ z + residual ----
  int ln = lane & 15, q = lane >> 4;
  int co0 = wave * 64;
  const short* a2base = outwb + (co0 + ln) * TC2 + q * 8;

  f32x4 acc[4];
#pragma unroll
  for (int i = 0; i < 4; ++i) acc[i] = (f32x4){0.f, 0.f, 0.f, 0.f};

#pragma unroll
  for (int c = 0; c < 8; ++c) {
    bf16x8 bv = *(const bf16x8*)(&zt[ln * DT_STR + c * 32 + q * 8]);
#pragma unroll
    for (int mt = 0; mt < 4; ++mt) {
      bf16x8 av = *(const bf16x8*)(a2base + (mt * 16) * TC2 + c * 32);
      acc[mt] = __builtin_amdgcn_mfma_f32_16x16x32_bf16(av, bv, acc[mt], 0, 0, 0);
    }
  }

  int hw0 = pixbase - n * (TH * TW);
#pragma unroll
  for (int mt = 0; mt < 4; ++mt) {
    int co = co0 + mt * 16 + q * 4;
#pragma unroll
    for (int r = 0; r < 4; ++r) {
      int addr = (n * TC2 + co + r) * (TH * TW) + hw0 + ln;
      out[addr] = x[addr] + siluf(acc[mt][r] + t3p[co + r]);
    }
  }
}

extern "C" void kernel_launch(void* const* d_in, const int* in_sizes, int n_in,
                              void* d_out, int out_size, void* d_ws, size_t ws_size,
                              hipStream_t stream)
{
  const float* x    = (const float*)d_in[0];
  const float* w1   = (const float*)d_in[1];
  const float* g1   = (const float*)d_in[2];
  const float* b1   = (const float*)d_in[3];
  const float* m1   = (const float*)d_in[4];
  const float* v1   = (const float*)d_in[5];
  const float* w2   = (const float*)d_in[6];
  const float* g2   = (const float*)d_in[7];
  const float* b2   = (const float*)d_in[8];
  const float* m2   = (const float*)d_in[9];
  const float* v2   = (const float*)d_in[10];
  const float* dww  = (const float*)d_in[11];
  const float* dwb  = (const float*)d_in[12];
  const float* lng  = (const float*)d_in[13];
  const float* lnb  = (const float*)d_in[14];
  const float* offw = (const float*)d_in[15];
  const float* offb = (const float*)d_in[16];
  const float* mskw = (const float*)d_in[17];
  const float* mskb = (const float*)d_in[18];
  const float* inw  = (const float*)d_in[19];
  const float* inb  = (const float*)d_in[20];
  const float* outw = (const float*)d_in[21];
  const float* outb = (const float*)d_in[22];
  const float* g3   = (const float*)d_in[23];
  const float* b3   = (const float*)d_in[24];
  const float* m3   = (const float*)d_in[25];
  const float* v3   = (const float*)d_in[26];

  float* ws  = (float*)d_ws;
  float* out = (float*)d_out;

  short* xpn    = (short*)(ws + OFF_XPAD);
  short* wbf    = (short*)(ws + OFF_WBF);
  short* w2b    = (short*)(ws + OFF_W2B);
  short* inwb   = (short*)(ws + OFF_INWB);
  short* outwb  = (short*)(ws + OFF_OUTWB);
  short* wcat16 = (short*)(ws + OFF_WCAT);
  short* y2b    = (short*)(ws + OFF_Y2N);
  float* raw    = ws + OFF_RAWN;
  short* xproj  = (short*)(ws + OFF_XPJ);   // moved off d_out: dcnpo reads xproj while writing out

  hipLaunchKernelGGL(k_prep, dim3(1836 + TN * THP * 8), dim3(256), 0, stream,
                     w1, g1, b1, m1, v1, w2, g2, b2, m2, v2,
                     dww, offw, offb, mskw, mskb, inw, outw, outb, g3, b3, m3, v3, x, ws);
  hipLaunchKernelGGL(k_cv12,     dim3(400),   dim3(256), 0, stream, xpn, wbf, w2b,
                     ws + OFF_T1, ws + OFF_T2, y2b);
  hipLaunchKernelGGL(k_pidw,     dim3(1200),  dim3(256), 0, stream, y2b, inwb, inb, xproj,
                     ws + OFF_DWT, dwb, lng, lnb, wcat16, ws + OFF_WCATB, raw);
  hipLaunchKernelGGL(k_dcnpo,    dim3(1600),  dim3(256), 0, stream, xproj, raw, outwb,
                     ws + OFF_T3P, x, out);
}

// Round 14
// 268.197 us; speedup vs baseline: 1.0408x; 1.0408x over previous
//
#include <hip/hip_runtime.h>
#include <cmath>

// Problem dims
#define TN 4
#define TC1 256
#define TCH 128
#define TC2 256
#define TH 80
#define TW 80
#define THP 82
#define TWP 84
#define NPIX (TN*TH*TW)   // 25600

// Workspace layout (float offsets). Total = 17,356,288 floats = 69.4 MB.
#define OFF_WBF   0         // bf16 wbf[co][tap*256+ci], s1-folded: 294912 shorts
#define OFF_W2B   294912    // bf16 [co][ci=128], s2-folded: 32768 shorts
#define OFF_INWB  327680    // bf16 [co][ci=256]: 65536 shorts
#define OFF_OUTWB 393216    // bf16 [co][ci=256], s3-folded: 65536 shorts
#define OFF_DWT   458752    // fp32 [tap][c] 2304
#define OFF_WCAT  461056    // bf16 [j<32][c=256] 8192 shorts
#define OFF_WCATB 467968    // fp32 27
#define OFF_T1    468128    // 128
#define OFF_T2    468512    // 256
#define OFF_T3P   469024    // 256
#define OFF_XPAD  469504    // bf16 NHWC padded x: ends 3,997,696
// aliases (liveness chain, stream order):
#define OFF_Y2N   7525888   // bf16 y2 [25600][256]
#define OFF_RAWN  10802688  // fp32 raw [25600][27]
#define OFF_ZN    11493888  // bf16 z [25600][256]

typedef __attribute__((ext_vector_type(8))) short bf16x8;
typedef __attribute__((ext_vector_type(4))) float f32x4;

__device__ __forceinline__ float siluf(float v) { return v / (1.f + expf(-v)); }
__device__ __forceinline__ short rnbf(float f) {
  unsigned u = __float_as_uint(f);
  unsigned r = (u + 0x7fffu + ((u >> 16) & 1u)) >> 16;
  return (short)r;
}
__device__ __forceinline__ float bf2f(short s) {
  return __uint_as_float(((unsigned)(unsigned short)s) << 16);
}

// ---------------- prep (weights) + padx (x -> bf16 NHWC padded), MERGED ----------------
__global__ __launch_bounds__(256) void k_prep(
    const float* __restrict__ w1, const float* __restrict__ g1, const float* __restrict__ b1,
    const float* __restrict__ m1, const float* __restrict__ v1,
    const float* __restrict__ w2, const float* __restrict__ g2, const float* __restrict__ b2,
    const float* __restrict__ m2, const float* __restrict__ v2,
    const float* __restrict__ dww, const float* __restrict__ offw, const float* __restrict__ offb,
    const float* __restrict__ mskw, const float* __restrict__ mskb,
    const float* __restrict__ inw, const float* __restrict__ outw, const float* __restrict__ outb,
    const float* __restrict__ g3, const float* __restrict__ b3,
    const float* __restrict__ m3, const float* __restrict__ v3,
    const float* __restrict__ x, float* __restrict__ ws)
{
  __shared__ short lds[80 * 40];
  if (blockIdx.x >= 1836) {
    // ---- padx body ----
    short* xpn = (short*)(ws + OFF_XPAD);
    int b = blockIdx.x - 1836;
    int cc = b & 7; int hp = (b >> 3) % THP; int n = b / (THP * 8);
    int c0 = cc * 32;
    int t = threadIdx.x;
    int h = hp - 1;
    bool hv = (h >= 0 && h < TH);
    if (hv) {
      for (int f = t; f < 640; f += 256) {          // 32 ci x 20 float4
        int ci = f / 20; int w4 = (f - ci * 20) * 4;
        float4 xv = *(const float4*)(x + ((n * TC1 + c0 + ci) * TH + h) * TW + w4);
        lds[(w4 + 0) * 40 + ci] = rnbf(xv.x);
        lds[(w4 + 1) * 40 + ci] = rnbf(xv.y);
        lds[(w4 + 2) * 40 + ci] = rnbf(xv.z);
        lds[(w4 + 3) * 40 + ci] = rnbf(xv.w);
      }
    }
    __syncthreads();
    short* op = xpn + ((n * THP + hp) * TWP) * TC2 + c0;
    for (int g = t; g < 672; g += 256) {            // 84 wp x 8 ci4
      int ci4 = (g & 7) * 4; int wp = g >> 3;
      short4 v = {0, 0, 0, 0};
      if (hv && wp >= 1 && wp <= TW) v = *(const short4*)(&lds[(wp - 1) * 40 + ci4]);
      *(short4*)(op + wp * TC2 + ci4) = v;
    }
    return;
  }
  // ---- prep body ----
  int i = blockIdx.x * 256 + threadIdx.x;
  if (i < 294912) {
    int co = i / 2304; int r = i - co * 2304;
    int tap = r >> 8; int ci = r & 255; int ky = tap / 3; int kx = tap - ky * 3;
    float s = g1[co] * __frsqrt_rn(v1[co] + 1e-5f);
    ((short*)(ws + OFF_WBF))[i] = rnbf(w1[((co * TC1 + ci) * 3 + ky) * 3 + kx] * s);
    return;
  }
  i -= 294912;
  if (i < 32768) {
    int co = i >> 7; int ci = i & 127;
    float s = g2[co] * __frsqrt_rn(v2[co] + 1e-5f);
    ((short*)(ws + OFF_W2B))[i] = rnbf(w2[co * TCH + ci] * s);
    return;
  }
  i -= 32768;
  if (i < 65536) {
    int co = i >> 8; int ci = i & 255;
    ((short*)(ws + OFF_INWB))[i] = rnbf(inw[co * TC2 + ci]);
    return;
  }
  i -= 65536;
  if (i < 65536) {
    int co = i >> 8; int ci = i & 255;
    float s = g3[co] * __frsqrt_rn(v3[co] + 1e-5f);
    ((short*)(ws + OFF_OUTWB))[i] = rnbf(outw[co * TC2 + ci] * s);
    return;
  }
  i -= 65536;
  if (i < 2304) { int c = i & 255; int j = i >> 8; ws[OFF_DWT + i] = dww[c * 9 + j]; return; }
  i -= 2304;
  if (i < 8192) {
    int c = i & 255; int j = i >> 8;
    float v = 0.f;
    if (j < 18) v = offw[j * 256 + c];
    else if (j < 27) v = mskw[(j - 18) * 256 + c];
    ((short*)(ws + OFF_WCAT))[i] = rnbf(v);
    return;
  }
  i -= 8192;
  if (i < 27) { ws[OFF_WCATB + i] = (i < 18) ? offb[i] : mskb[i - 18]; return; }
  i -= 27;
  if (i < 128) { float s = g1[i] / sqrtf(v1[i] + 1e-5f); ws[OFF_T1 + i] = b1[i] - m1[i] * s; return; }
  i -= 128;
  if (i < 256) { float s = g2[i] / sqrtf(v2[i] + 1e-5f); ws[OFF_T2 + i] = b2[i] - m2[i] * s; return; }
  i -= 256;
  if (i < 256) { float s = g3[i] / sqrtf(v3[i] + 1e-5f); ws[OFF_T3P + i] = outb[i] * s + b3[i] - m3[i] * s; return; }
}

// ---------------- cv1 + cv2 FUSED: halo MFMA conv -> y1 tile in LDS -> K=128 GEMM -> y2 ----------------
#define BH_STR 40    // halo pixel stride (shorts)
#define BH_PIX 108   // 6 x 18 halo pixels
#define BH_ELE (BH_PIX * BH_STR)   // 4320 shorts per buffer
#define Y1_STR 136   // y1 tile row stride (shorts): 128 + 8 pad
__global__ __launch_bounds__(256) void k_cv12(const short* __restrict__ xpn, const short* __restrict__ wbf,
                                              const short* __restrict__ w2b,
                                              const float* __restrict__ t1v, const float* __restrict__ t2v,
                                              short* __restrict__ y2b)
{
  __shared__ short U[64 * Y1_STR];   // 17,408 B; aliases Bh[2][BH_ELE] (17,280 B)

  int b = blockIdx.x;
  int wt = b % 5; b /= 5; int ht = b % 20; int n = b / 20;
  int w0 = wt * 16, h0 = ht * 4;

  int tid = threadIdx.x;
  int wave = tid >> 6, lane = tid & 63;
  int ln = lane & 15, q = lane >> 4;
  int co0 = wave * 32;

  // ---- phase 1: cv1 ----
  int u0 = tid, u1 = tid + 256;
  int p0 = u0 >> 2, s0 = u0 & 3;
  int p1 = u1 >> 2, s1 = u1 & 3;
  int hh0 = p0 / 18, ww0 = p0 - hh0 * 18;
  int hh1 = p1 / 18, ww1 = p1 - hh1 * 18;
  const short* sb0 = xpn + ((n * THP + h0 + hh0) * TWP + (w0 + ww0)) * 256 + s0 * 8;
  const short* sb1 = xpn + ((n * THP + h0 + hh1) * TWP + (w0 + ww1)) * 256 + s1 * 8;
  bool hasu1 = (u1 < 432);
  int d0 = p0 * BH_STR + s0 * 8;
  int d1 = p1 * BH_STR + s1 * 8;

  const short* abase = wbf + (co0 + ln) * 2304 + q * 8;

  f32x4 acc[2][4];
#pragma unroll
  for (int i = 0; i < 2; ++i)
#pragma unroll
    for (int j = 0; j < 4; ++j) acc[i][j] = (f32x4){0.f, 0.f, 0.f, 0.f};

  bf16x8 rb0 = *(const bf16x8*)(sb0);
  bf16x8 rb1 = {0, 0, 0, 0, 0, 0, 0, 0};
  if (hasu1) rb1 = *(const bf16x8*)(sb1);
  *(bf16x8*)(&U[d0]) = rb0;
  if (hasu1) *(bf16x8*)(&U[d1]) = rb1;
  __syncthreads();

  for (int cc = 0; cc < 8; ++cc) {
    int cur = cc & 1;
    bf16x8 af[9][2];
#pragma unroll
    for (int tap = 0; tap < 9; ++tap)
#pragma unroll
      for (int mt = 0; mt < 2; ++mt)
        af[tap][mt] = *(const bf16x8*)(abase + (mt * 16) * 2304 + tap * 256 + cc * 32);
    if (cc < 7) {
      rb0 = *(const bf16x8*)(sb0 + (cc + 1) * 32);
      if (hasu1) rb1 = *(const bf16x8*)(sb1 + (cc + 1) * 32);
    }
#pragma unroll
    for (int tap = 0; tap < 9; ++tap) {
      const int ky = tap / 3, kx = tap - (tap / 3) * 3;
      bf16x8 bv[4];
#pragma unroll
      for (int nt = 0; nt < 4; ++nt) {
        int pr = nt * 16 + ln;
        int hr = pr >> 4, wc = pr & 15;
        bv[nt] = *(const bf16x8*)(&U[cur * BH_ELE + ((hr + ky) * 18 + (wc + kx)) * BH_STR + q * 8]);
      }
#pragma unroll
      for (int mt = 0; mt < 2; ++mt)
#pragma unroll
        for (int nt = 0; nt < 4; ++nt)
          acc[mt][nt] = __builtin_amdgcn_mfma_f32_16x16x32_bf16(af[tap][mt], bv[nt], acc[mt][nt], 0, 0, 0);
    }
    if (cc < 7) {
      *(bf16x8*)(&U[(cur ^ 1) * BH_ELE + d0]) = rb0;
      if (hasu1) *(bf16x8*)(&U[(cur ^ 1) * BH_ELE + d1]) = rb1;
      __syncthreads();
    }
  }

  // ---- phase 2: y1 tile -> LDS, K=128 GEMM -> y2 ----
  __syncthreads();
#pragma unroll
  for (int mt = 0; mt < 2; ++mt) {
    int co = co0 + mt * 16 + q * 4;
    float t0 = t1v[co], t1 = t1v[co + 1], t2 = t1v[co + 2], t3 = t1v[co + 3];
#pragma unroll
    for (int nt = 0; nt < 4; ++nt) {
      int px = nt * 16 + ln;
      short4 p;
      p.x = rnbf(siluf(acc[mt][nt][0] + t0));
      p.y = rnbf(siluf(acc[mt][nt][1] + t1));
      p.z = rnbf(siluf(acc[mt][nt][2] + t2));
      p.w = rnbf(siluf(acc[mt][nt][3] + t3));
      *(short4*)(&U[px * Y1_STR + co]) = p;
    }
  }
  __syncthreads();

  int coh2 = wave * 64;
  const short* a2base = w2b + (coh2 + ln) * TCH + q * 8;

  f32x4 acc2[4][4];
#pragma unroll
  for (int i = 0; i < 4; ++i)
#pragma unroll
    for (int j = 0; j < 4; ++j) acc2[i][j] = (f32x4){0.f, 0.f, 0.f, 0.f};

#pragma unroll
  for (int c = 0; c < 4; ++c) {
    bf16x8 a2[4], b2[4];
#pragma unroll
    for (int mt = 0; mt < 4; ++mt)
      a2[mt] = *(const bf16x8*)(a2base + (mt * 16) * TCH + c * 32);
#pragma unroll
    for (int nt = 0; nt < 4; ++nt)
      b2[nt] = *(const bf16x8*)(&U[(nt * 16 + ln) * Y1_STR + c * 32 + q * 8]);
#pragma unroll
    for (int mt = 0; mt < 4; ++mt)
#pragma unroll
      for (int nt = 0; nt < 4; ++nt)
        acc2[mt][nt] = __builtin_amdgcn_mfma_f32_16x16x32_bf16(a2[mt], b2[nt], acc2[mt][nt], 0, 0, 0);
  }

#pragma unroll
  for (int mt = 0; mt < 4; ++mt) {
    int co = coh2 + mt * 16 + q * 4;
    float t0 = t2v[co], t1 = t2v[co + 1], t2 = t2v[co + 2], t3 = t2v[co + 3];
#pragma unroll
    for (int nt = 0; nt < 4; ++nt) {
      int pr = nt * 16 + ln;
      int hr = pr >> 4, wc = pr & 15;
      int pix = (n * TH + h0 + hr) * TW + (w0 + wc);
      short4 p;
      p.x = rnbf(siluf(acc2[mt][nt][0] + t0));
      p.y = rnbf(siluf(acc2[mt][nt][1] + t1));
      p.z = rnbf(siluf(acc2[mt][nt][2] + t2));
      p.w = rnbf(siluf(acc2[mt][nt][3] + t3));
      *(short4*)(y2b + pix * TC2 + co) = p;
    }
  }
}

// ---------------- proj_in + dwln/offmask MERGED (independent consumers of y2b) ----------------
#define A_STR 40
#define DT_STR 264
__global__ __launch_bounds__(256) void k_pidw(
    const short* __restrict__ y2b, const short* __restrict__ inwb, const float* __restrict__ inb,
    short* __restrict__ xproj,
    const float* __restrict__ dwt, const float* __restrict__ dwb, const float* __restrict__ lng,
    const float* __restrict__ lnb, const short* __restrict__ wcatb16, const float* __restrict__ wcatb,
    float* __restrict__ raw)
{
  __shared__ short smem[4 * 128 * A_STR];   // 81920 B union

  int tid = threadIdx.x;
  int wave = tid >> 6, lane = tid & 63;

  if (blockIdx.x < 400) {
    // ======== proj_in body ========
    short (*As)[128 * A_STR] = (short(*)[128 * A_STR])(smem);
    short (*Bs)[128 * A_STR] = (short(*)[128 * A_STR])(smem + 2 * 128 * A_STR);

    int b = blockIdx.x;
    int ch = b & 1; int pt = b >> 1;
    int co_base = ch * 128;
    int pix0 = pt * 128;

    int ln = lane & 15, q = lane >> 4;
    int coh = (wave & 1) * 64;
    int pxh = (wave >> 1) * 64;

    int srow = tid >> 1;
    int ssub = (tid & 1) * 16;
    const short* arow = inwb + (co_base + srow) * TC2 + ssub;
    const short* brow = y2b + (pix0 + srow) * TC2 + ssub;

    f32x4 acc[4][4];
#pragma unroll
    for (int i = 0; i < 4; ++i)
#pragma unroll
      for (int j = 0; j < 4; ++j) acc[i][j] = (f32x4){0.f, 0.f, 0.f, 0.f};

    bf16x8 ra0, ra1, rb0, rb1;
    auto grab = [&](int c) {
      const short* ap = arow + c * 32;
      const short* bp = brow + c * 32;
      ra0 = *(const bf16x8*)(ap);
      ra1 = *(const bf16x8*)(ap + 8);
      rb0 = *(const bf16x8*)(bp);
      rb1 = *(const bf16x8*)(bp + 8);
    };
    auto put = [&](int buf) {
      int o = srow * A_STR + ssub;
      *(bf16x8*)(&As[buf][o])     = ra0;
      *(bf16x8*)(&As[buf][o + 8]) = ra1;
      *(bf16x8*)(&Bs[buf][o])     = rb0;
      *(bf16x8*)(&Bs[buf][o + 8]) = rb1;
    };
    auto comp = [&](int buf) {
      bf16x8 af[4], bfv[4];
#pragma unroll
      for (int mt = 0; mt < 4; ++mt)
        af[mt] = *(const bf16x8*)(&As[buf][(coh + mt * 16 + ln) * A_STR + q * 8]);
#pragma unroll
      for (int nt = 0; nt < 4; ++nt)
        bfv[nt] = *(const bf16x8*)(&Bs[buf][(pxh + nt * 16 + ln) * A_STR + q * 8]);
#pragma unroll
      for (int mt = 0; mt < 4; ++mt)
#pragma unroll
        for (int nt = 0; nt < 4; ++nt)
          acc[mt][nt] = __builtin_amdgcn_mfma_f32_16x16x32_bf16(af[mt], bfv[nt], acc[mt][nt], 0, 0, 0);
    };

    const int NCH = TC2 / 32;
    grab(0);
    put(0);
    __syncthreads();
    for (int c = 0; c < NCH; ++c) {
      if (c < NCH - 1) grab(c + 1);
      comp(c & 1);
      if (c < NCH - 1) {
        __syncthreads();
        put((c + 1) & 1);
        __syncthreads();
      }
    }

#pragma unroll
    for (int mt = 0; mt < 4; ++mt) {
      int co = co_base + coh + mt * 16 + q * 4;
      float b0 = inb[co], b1 = inb[co + 1], b2 = inb[co + 2], b3 = inb[co + 3];
#pragma unroll
      for (int nt = 0; nt < 4; ++nt) {
        int pix = pix0 + pxh + nt * 16 + ln;
        short4 p;
        p.x = rnbf(acc[mt][nt][0] + b0);
        p.y = rnbf(acc[mt][nt][1] + b1);
        p.z = rnbf(acc[mt][nt][2] + b2);
        p.w = rnbf(acc[mt][nt][3] + b3);
        *(short4*)(xproj + pix * TC2 + co) = p;
      }
    }
    return;
  }

  // ======== dwom body ========
  short* dt = smem;   // 32 x DT_STR = 8448 shorts

  int half = lane >> 5;
  int c0 = (lane & 31) * 8;
  int pix0 = (blockIdx.x - 400) * 32;

  float4 db0 = *(const float4*)(dwb + c0);
  float4 db1 = *(const float4*)(dwb + c0 + 4);
  float4 g0 = *(const float4*)(lng + c0);
  float4 g1 = *(const float4*)(lng + c0 + 4);
  float4 lb0 = *(const float4*)(lnb + c0);
  float4 lb1 = *(const float4*)(lnb + c0 + 4);
  float gv[8] = {g0.x, g0.y, g0.z, g0.w, g1.x, g1.y, g1.z, g1.w};
  float bvv[8] = {lb0.x, lb0.y, lb0.z, lb0.w, lb1.x, lb1.y, lb1.z, lb1.w};
  const float is2 = 0.70710678118654752f;

  for (int r = 0; r < 4; ++r) {
    int pl = wave * 8 + half * 4 + r;
    int pix = pix0 + pl;
    int w = pix % TW; int h = (pix / TW) % TH; int n = pix / (TH * TW);
    float v[8] = {db0.x, db0.y, db0.z, db0.w, db1.x, db1.y, db1.z, db1.w};
#pragma unroll
    for (int dy = 0; dy < 3; ++dy) {
#pragma unroll
      for (int dx = 0; dx < 3; ++dx) {
        int hh = h + dy - 1, ww = w + dx - 1;
        bool ok = (hh >= 0) & (hh < TH) & (ww >= 0) & (ww < TW);
        int off = ok ? (((n * TH + hh) * TW + ww) * TC2 + c0) : c0;
        bf16x8 yv = *(const bf16x8*)(y2b + off);
        float m = ok ? 1.f : 0.f;
        const float* wp = dwt + (dy * 3 + dx) * TC2 + c0;
        float4 w0 = *(const float4*)(wp);
        float4 w1 = *(const float4*)(wp + 4);
        v[0] += bf2f(yv[0]) * w0.x * m;
        v[1] += bf2f(yv[1]) * w0.y * m;
        v[2] += bf2f(yv[2]) * w0.z * m;
        v[3] += bf2f(yv[3]) * w0.w * m;
        v[4] += bf2f(yv[4]) * w1.x * m;
        v[5] += bf2f(yv[5]) * w1.y * m;
        v[6] += bf2f(yv[6]) * w1.z * m;
        v[7] += bf2f(yv[7]) * w1.w * m;
      }
    }
    float sv = 0.f, sq = 0.f;
#pragma unroll
    for (int i = 0; i < 8; ++i) { sv += v[i]; sq += v[i] * v[i]; }
#pragma unroll
    for (int o = 16; o > 0; o >>= 1) { sv += __shfl_xor(sv, o); sq += __shfl_xor(sq, o); }
    float mu = sv * (1.f / 256.f);
    float var = sq * (1.f / 256.f) - mu * mu;
    float rs = 1.f / sqrtf(var + 1e-6f);
    bf16x8 o8;
#pragma unroll
    for (int i = 0; i < 8; ++i) {
      float nv = (v[i] - mu) * rs * gv[i] + bvv[i];
      o8[i] = rnbf(0.5f * nv * (1.f + erff(nv * is2)));
    }
    *(bf16x8*)(&dt[pl * DT_STR + c0]) = o8;
  }
  __syncthreads();

  int ln = lane & 15, q = lane >> 4;
  int g = wave & 1;
  int jbase = (wave >> 1) * 16;

  f32x4 acc = {0.f, 0.f, 0.f, 0.f};
  const short* ap = wcatb16 + (jbase + ln) * 256 + q * 8;
  const short* bp = &dt[(g * 16 + ln) * DT_STR + q * 8];
#pragma unroll
  for (int kk = 0; kk < 256; kk += 32) {
    bf16x8 a  = *(const bf16x8*)(ap + kk);
    bf16x8 bf = *(const bf16x8*)(bp + kk);
    acc = __builtin_amdgcn_mfma_f32_16x16x32_bf16(a, bf, acc, 0, 0, 0);
  }

  int pix = pix0 + g * 16 + ln;
#pragma unroll
  for (int r = 0; r < 4; ++r) {
    int j = jbase + q * 4 + r;
    if (j < 27) raw[pix * 27 + j] = acc[r] + wcatb[j];
  }
}

// ---------------- DCN core: 8 px/block setup, 2 px/wave, 8 ch/lane (16B gathers) ----------------
__global__ __launch_bounds__(256) void k_dcn(const short* __restrict__ xproj, const float* __restrict__ raw,
                                             short* __restrict__ z)
{
  __shared__ int2 sp[8][36];
  int tid = threadIdx.x;
  int pixbase = blockIdx.x * 8;

  for (int j = tid; j < 288; j += 256) {
    int pxl = j / 36, t = j - pxl * 36;
    int pix = pixbase + pxl;
    int w = pix % TW; int h = (pix / TW) % TH;
    const float* r = raw + pix * 27;
    int k = t >> 2, tap = t & 3;
    int tx = tap & 1, ty = tap >> 1;
    float mx = r[18];
#pragma unroll
    for (int kk = 1; kk < 9; ++kk) mx = fmaxf(mx, r[18 + kk]);
    float sum = 0.f, ek = 0.f;
#pragma unroll
    for (int kk = 0; kk < 9; ++kk) {
      float ee = expf(r[18 + kk] - mx);
      sum += ee;
      if (kk == k) ek = ee;
    }
    float mk = ek / sum;
    float px = (float)(w + k / 3) + r[2 * k];
    float py = (float)(h + k % 3) + r[2 * k + 1];
    float x0f = floorf(px), y0f = floorf(py);
    float lw = px - x0f, lh = py - y0f;
    int x0 = (int)x0f + tx, y0 = (int)y0f + ty;
    float wt = mk * (tx ? lw : 1.f - lw) * (ty ? lh : 1.f - lh);
    bool valid = (x0 >= 1) & (x0 <= TW) & (y0 >= 1) & (y0 <= TH);
    int2 pr;
    pr.x = valid ? (((y0 - 1) * TW + (x0 - 1)) * TC2) : 0;
    pr.y = valid ? __float_as_int(wt) : 0;
    sp[pxl][t] = pr;
  }
  __syncthreads();

  int wave = tid >> 6, lane = tid & 63;
  int half = lane >> 5;
  int pxl = wave * 2 + half;
  int pix = pixbase + pxl;
  int n = pix / (TH * TW);
  int c0 = (lane & 31) * 8;
  const short* xb = xproj + n * (TH * TW * TC2) + c0;

  float a[8] = {0.f, 0.f, 0.f, 0.f, 0.f, 0.f, 0.f, 0.f};
#pragma unroll
  for (int t = 0; t < 36; ++t) {
    int2 pr = sp[pxl][t];
    float wt = __int_as_float(pr.y);
    bf16x8 v = *(const bf16x8*)(xb + pr.x);
#pragma unroll
    for (int i = 0; i < 8; ++i) a[i] += wt * bf2f(v[i]);
  }
  bf16x8 o8;
#pragma unroll
  for (int i = 0; i < 8; ++i) o8[i] = rnbf(a[i]);
  *(bf16x8*)(z + pix * TC2 + c0) = o8;
}

// ---------------- output_proj: LDS-staged MFMA + BN + SiLU + residual ----------------
__global__ __launch_bounds__(256) void k_proj_out(const short* __restrict__ zb, const short* __restrict__ outwb,
                                                  const float* __restrict__ t3p,
                                                  const float* __restrict__ x, float* __restrict__ out)
{
  __shared__ short As[2][128 * A_STR];
  __shared__ short Bs[2][128 * A_STR];

  int b = blockIdx.x;
  int ch = b & 1; int pt = b >> 1;
  int co_base = ch * 128;
  int pix0 = pt * 128;

  int tid = threadIdx.x;
  int wave = tid >> 6, lane = tid & 63;
  int ln = lane & 15, q = lane >> 4;
  int coh = (wave & 1) * 64;
  int pxh = (wave >> 1) * 64;

  int srow = tid >> 1;
  int ssub = (tid & 1) * 16;
  const short* arow = outwb + (co_base + srow) * TC2 + ssub;
  const short* brow = zb + (pix0 + srow) * TC2 + ssub;

  f32x4 acc[4][4];
#pragma unroll
  for (int i = 0; i < 4; ++i)
#pragma unroll
    for (int j = 0; j < 4; ++j) acc[i][j] = (f32x4){0.f, 0.f, 0.f, 0.f};

  bf16x8 ra0, ra1, rb0, rb1;
  auto grab = [&](int c) {
    const short* ap = arow + c * 32;
    const short* bp = brow + c * 32;
    ra0 = *(const bf16x8*)(ap);
    ra1 = *(const bf16x8*)(ap + 8);
    rb0 = *(const bf16x8*)(bp);
    rb1 = *(const bf16x8*)(bp + 8);
  };
  auto put = [&](int buf) {
    int o = srow * A_STR + ssub;
    *(bf16x8*)(&As[buf][o])     = ra0;
    *(bf16x8*)(&As[buf][o + 8]) = ra1;
    *(bf16x8*)(&Bs[buf][o])     = rb0;
    *(bf16x8*)(&Bs[buf][o + 8]) = rb1;
  };
  auto comp = [&](int buf) {
    bf16x8 af[4], bfv[4];
#pragma unroll
    for (int mt = 0; mt < 4; ++mt)
      af[mt] = *(const bf16x8*)(&As[buf][(coh + mt * 16 + ln) * A_STR + q * 8]);
#pragma unroll
    for (int nt = 0; nt < 4; ++nt)
      bfv[nt] = *(const bf16x8*)(&Bs[buf][(pxh + nt * 16 + ln) * A_STR + q * 8]);
#pragma unroll
    for (int mt = 0; mt < 4; ++mt)
#pragma unroll
      for (int nt = 0; nt < 4; ++nt)
        acc[mt][nt] = __builtin_amdgcn_mfma_f32_16x16x32_bf16(af[mt], bfv[nt], acc[mt][nt], 0, 0, 0);
  };

  const int NCH = TC2 / 32;
  grab(0);
  put(0);
  __syncthreads();
  for (int c = 0; c < NCH; ++c) {
    if (c < NCH - 1) grab(c + 1);
    comp(c & 1);
    if (c < NCH - 1) {
      __syncthreads();
      put((c + 1) & 1);
      __syncthreads();
    }
  }

  // ---- epilogue: wave-private LDS transpose -> coalesced 256B x-load + out-store ----
  __syncthreads();
  float* tb = (float*)(&As[0][0]);
  float* wb = tb + wave * 1056;
  int pixw = pix0 + pxh;
  int nn = pixw / (TH * TW);
  int hw0 = pixw - nn * (TH * TW);

#pragma unroll
  for (int mt = 0; mt < 4; ++mt) {
#pragma unroll
    for (int nt = 0; nt < 4; ++nt)
#pragma unroll
      for (int r = 0; r < 4; ++r)
        wb[(q * 4 + r) * 66 + nt * 16 + ln] = acc[mt][nt][r];
    int co = co_base + coh + mt * 16;
#pragma unroll
    for (int cl = 0; cl < 16; ++cl) {
      float vv = wb[cl * 66 + lane];
      int addr = (nn * TC2 + co + cl) * (TH * TW) + hw0 + lane;
      out[addr] = x[addr] + siluf(vv + t3p[co + cl]);
    }
  }
}

extern "C" void kernel_launch(void* const* d_in, const int* in_sizes, int n_in,
                              void* d_out, int out_size, void* d_ws, size_t ws_size,
                              hipStream_t stream)
{
  const float* x    = (const float*)d_in[0];
  const float* w1   = (const float*)d_in[1];
  const float* g1   = (const float*)d_in[2];
  const float* b1   = (const float*)d_in[3];
  const float* m1   = (const float*)d_in[4];
  const float* v1   = (const float*)d_in[5];
  const float* w2   = (const float*)d_in[6];
  const float* g2   = (const float*)d_in[7];
  const float* b2   = (const float*)d_in[8];
  const float* m2   = (const float*)d_in[9];
  const float* v2   = (const float*)d_in[10];
  const float* dww  = (const float*)d_in[11];
  const float* dwb  = (const float*)d_in[12];
  const float* lng  = (const float*)d_in[13];
  const float* lnb  = (const float*)d_in[14];
  const float* offw = (const float*)d_in[15];
  const float* offb = (const float*)d_in[16];
  const float* mskw = (const float*)d_in[17];
  const float* mskb = (const float*)d_in[18];
  const float* inw  = (const float*)d_in[19];
  const float* inb  = (const float*)d_in[20];
  const float* outw = (const float*)d_in[21];
  const float* outb = (const float*)d_in[22];
  const float* g3   = (const float*)d_in[23];
  const float* b3   = (const float*)d_in[24];
  const float* m3   = (const float*)d_in[25];
  const float* v3   = (const float*)d_in[26];

  float* ws  = (float*)d_ws;
  float* out = (float*)d_out;

  short* xpn    = (short*)(ws + OFF_XPAD);
  short* wbf    = (short*)(ws + OFF_WBF);
  short* w2b    = (short*)(ws + OFF_W2B);
  short* inwb   = (short*)(ws + OFF_INWB);
  short* outwb  = (short*)(ws + OFF_OUTWB);
  short* wcat16 = (short*)(ws + OFF_WCAT);
  short* y2b    = (short*)(ws + OFF_Y2N);
  float* raw    = ws + OFF_RAWN;
  short* zb     = (short*)(ws + OFF_ZN);
  short* xproj  = (short*)d_out;

  hipLaunchKernelGGL(k_prep, dim3(1836 + TN * THP * 8), dim3(256), 0, stream,
                     w1, g1, b1, m1, v1, w2, g2, b2, m2, v2,
                     dww, offw, offb, mskw, mskb, inw, outw, outb, g3, b3, m3, v3, x, ws);
  hipLaunchKernelGGL(k_cv12,     dim3(400),   dim3(256), 0, stream, xpn, wbf, w2b,
                     ws + OFF_T1, ws + OFF_T2, y2b);
  hipLaunchKernelGGL(k_pidw,     dim3(1200),  dim3(256), 0, stream, y2b, inwb, inb, xproj,
                     ws + OFF_DWT, dwb, lng, lnb, wcat16, ws + OFF_WCATB, raw);
  hipLaunchKernelGGL(k_dcn,      dim3(3200),  dim3(256), 0, stream, xproj, raw, zb);
  hipLaunchKernelGGL(k_proj_out, dim3(400),   dim3(256), 0, stream, zb, outwb, ws + OFF_T3P, x, out);
}